// Round 6
// baseline (377.336 us; speedup 1.0000x reference)
//
#include <hip/hip_runtime.h>
#include <hip/hip_bf16.h>

// Fourier-KAN, round 6: GEMM M=32768 N=64 K=8192 with on-the-fly A.
// Math/fragments identical to verified rounds 2-5 (absmax 0.03125):
//   k = i*16 + t*8 + g; mfma_f32_32x32x16_bf16; A/B slot-symmetric k map;
//   C/D col=lane&31, row=(reg&3)+8*(reg>>2)+4*(lane>>5).
// NEW structure: wave-contiguous K-split (wave q owns i in [64q,64q+64)).
//  - B: per-wave CONTIGUOUS 128KB stream from ws (prep reordered), loaded
//    global->reg coalesced 16B/lane, distance-4 pipeline in named regs.
//  - X: wave-PRIVATE LDS transpose staging: per 8-i batch, 2 coalesced
//    float4 loads -> pad-65 LDS, double-buffered. Wave-synchronous: the
//    main loop has ZERO barriers (round 4's convoy) and ZERO gathers
//    (round 5's killer). LDS reused for the final tree reduction.

#define N_B 32768
#define N_I 512
#define N_O 64

typedef short bf16x8 __attribute__((ext_vector_type(8)));
typedef float f32x4  __attribute__((ext_vector_type(4)));
typedef float f32x16 __attribute__((ext_vector_type(16)));
typedef int   i32x4  __attribute__((ext_vector_type(4)));

// hardware packed f32->bf16 (RNE)
__device__ __forceinline__ int cvtpk(float lo, float hi) {
    int r;
    asm("v_cvt_pk_bf16_f32 %0, %1, %2" : "=v"(r) : "v"(lo), "v"(hi));
    return r;
}

// ---------------- prep: C (f32) -> ws (bf16, wave-contiguous streams) --------
// ws 16B-slot [q*8192 + c*128 + f*64 + l] = bf16( C[t=l>>5][i=q*64+c][n=f*32+(l&31)][g=0..7] )
__global__ __launch_bounds__(256)
void fkan_prep(const float* __restrict__ C, int4* __restrict__ ws) {
    const int tid = blockIdx.x * 256 + threadIdx.x;   // 65536 threads
    const int t = tid >> 15;
    const int i = (tid >> 6) & 511;
    const int n = tid & 63;
    const float* src = C + ((size_t)(t * N_I + i) * N_O + n) * 8;
    const float4 v0 = *(const float4*)(src);
    const float4 v1 = *(const float4*)(src + 4);
    int4 w;
    w.x = cvtpk(v0.x, v0.y);
    w.y = cvtpk(v0.z, v0.w);
    w.z = cvtpk(v1.x, v1.y);
    w.w = cvtpk(v1.z, v1.w);
    const int q = i >> 6, c = i & 63, f = n >> 5, l = t * 32 + (n & 31);
    ws[q * 8192 + c * 128 + f * 64 + l] = w;
}

// ---------------- main ----------------
// branchless cos/sin Chebyshev chain -> packed bf16 A-fragment (freqs 1..8)
__device__ __forceinline__ bf16x8 trigfrag(float x, int h) {
    const float r  = x * 0.15915494309189535f;   // revolutions
    const float s1 = __builtin_amdgcn_sinf(r);
    const float c1 = __builtin_amdgcn_cosf(r);
    const float t2 = c1 + c1;
    const float p0 = h ? 0.f : 1.f;
    const float p1 = h ? s1  : c1;
    const float p2 = __builtin_fmaf(t2, p1, -p0);
    const float p3 = __builtin_fmaf(t2, p2, -p1);
    const float p4 = __builtin_fmaf(t2, p3, -p2);
    const float p5 = __builtin_fmaf(t2, p4, -p3);
    const float p6 = __builtin_fmaf(t2, p5, -p4);
    const float p7 = __builtin_fmaf(t2, p6, -p5);
    const float p8 = __builtin_fmaf(t2, p7, -p6);
    union { int d[4]; bf16x8 v; } u;
    u.d[0] = cvtpk(p1, p2);
    u.d[1] = cvtpk(p3, p4);
    u.d[2] = cvtpk(p5, p6);
    u.d[3] = cvtpk(p7, p8);
    return u.v;
}

// one K-step: 2 B-frags (regs), 2 A-frags (trig), 4 MFMAs
__device__ __forceinline__ void compute4(i32x4 b0r, i32x4 b1r, float xa, float xb,
                                         int h, f32x16* acc) {
    union { i32x4 d; bf16x8 v; } u0, u1;
    u0.d = b0r; u1.d = b1r;
    const bf16x8 A0 = trigfrag(xa, h);
    const bf16x8 A1 = trigfrag(xb, h);
    __builtin_amdgcn_s_setprio(1);
    acc[0] = __builtin_amdgcn_mfma_f32_32x32x16_bf16(A0, u0.v, acc[0], 0, 0, 0);
    acc[1] = __builtin_amdgcn_mfma_f32_32x32x16_bf16(A0, u1.v, acc[1], 0, 0, 0);
    acc[2] = __builtin_amdgcn_mfma_f32_32x32x16_bf16(A1, u0.v, acc[2], 0, 0, 0);
    acc[3] = __builtin_amdgcn_mfma_f32_32x32x16_bf16(A1, u1.v, acc[3], 0, 0, 0);
    __builtin_amdgcn_s_setprio(0);
}

__device__ __forceinline__ void dumpAcc(float* base, const f32x16* acc, int l) {
    #pragma unroll
    for (int fr = 0; fr < 4; ++fr) {
        union { f32x16 v; f32x4 s[4]; } u; u.v = acc[fr];
        #pragma unroll
        for (int rg = 0; rg < 4; ++rg)
            *(f32x4*)(base + fr * 1024 + rg * 256 + l * 4) = u.s[rg];
    }
}
__device__ __forceinline__ void addAcc(const float* base, f32x16* acc, int l) {
    #pragma unroll
    for (int fr = 0; fr < 4; ++fr) {
        union { f32x16 v; f32x4 s[4]; } u; u.v = acc[fr];
        #pragma unroll
        for (int rg = 0; rg < 4; ++rg)
            u.s[rg] += *(const f32x4*)(base + fr * 1024 + rg * 256 + l * 4);
        acc[fr] = u.v;
    }
}

// x read for step c from this wave's private transpose buffer
#define XRD(c, xa_, xb_)                                                    \
    {                                                                       \
        const float* Xr_ = Xbase + ((((c) >> 3) & 1) * 520 + ((c) & 7) * 65); \
        xa_ = Xr_[lane31];                                                  \
        xb_ = Xr_[32 + lane31];                                             \
    }

// compute step c with slot S, then refill S with step c+4
#define STEP_L(S, c)                                                        \
    {                                                                       \
        float xa_, xb_;                                                     \
        XRD(c, xa_, xb_);                                                   \
        compute4(S##a, S##b, xa_, xb_, h, acc);                             \
        const int cn_ = (c) + 4;                                            \
        S##a = bptr[cn_ * 128];                                             \
        S##b = bptr[cn_ * 128 + 64];                                        \
    }
// compute step c with slot S, no refill (tail)
#define STEP_N(S, c)                                                        \
    {                                                                       \
        float xa_, xb_;                                                     \
        XRD(c, xa_, xb_);                                                   \
        compute4(S##a, S##b, xa_, xb_, h, acc);                             \
    }

__global__ __launch_bounds__(512, 4)
void fkan_main(const float* __restrict__ X, const i32x4* __restrict__ Wf,
               const float* __restrict__ bias, float* __restrict__ out) {
    __shared__ __align__(16) float smem[16384];   // Xt (8 waves x 2x8x65) + reduction overlay

    const int tid    = threadIdx.x;
    const int l      = tid & 63;
    const int q      = tid >> 6;     // wave id; owns i in [64q, 64q+64)
    const int h      = l >> 5;       // 0: cos, 1: sin
    const int lane31 = l & 31;
    const int row0   = blockIdx.x * 64;

    float* Xbase = smem + q * 1040;                // 2 bufs x 8 ilocs x 65 (pad)
    const i32x4* bptr = Wf + q * 8192 + l;         // contiguous per-wave B stream

    // coalesced X batch sources: lane pair covers one row's 8 floats
    const float* xg0 = X + (size_t)(row0 + (l >> 1)) * N_I + q * 64 + (l & 1) * 4;
    const float* xg1 = xg0 + (size_t)32 * N_I;

    f32x16 acc[4];
    #pragma unroll
    for (int a = 0; a < 4; ++a)
        #pragma unroll
        for (int r = 0; r < 16; ++r) acc[a][r] = 0.f;

    // ---- prologue: X batch 0 -> buf0 (wave-private, no barrier) ----
    {
        const f32x4 g0 = *(const f32x4*)(xg0);
        const f32x4 g1 = *(const f32x4*)(xg1);
        #pragma unroll
        for (int m = 0; m < 4; ++m) {
            Xbase[((l & 1) * 4 + m) * 65 + (l >> 1)]      = g0[m];
            Xbase[((l & 1) * 4 + m) * 65 + 32 + (l >> 1)] = g1[m];
        }
    }
    // ---- prologue: B steps 0..3 into named slots ----
    i32x4 B0a = bptr[0 * 128], B0b = bptr[0 * 128 + 64];
    i32x4 B1a = bptr[1 * 128], B1b = bptr[1 * 128 + 64];
    i32x4 B2a = bptr[2 * 128], B2b = bptr[2 * 128 + 64];
    i32x4 B3a = bptr[3 * 128], B3b = bptr[3 * 128 + 64];

    // ---- barrier-free main loop: batches b=0..6 (8 steps each) ----
    #pragma unroll 1
    for (int b = 0; b < 7; ++b) {
        const int c0 = b * 8;
        // issue next X batch loads early (latency hides under quad A)
        const f32x4 g0 = *(const f32x4*)(xg0 + (b + 1) * 8);
        const f32x4 g1 = *(const f32x4*)(xg1 + (b + 1) * 8);

        STEP_L(B0, c0 + 0)
        STEP_L(B1, c0 + 1)
        STEP_L(B2, c0 + 2)
        STEP_L(B3, c0 + 3)

        // write next X batch into the other buffer (wave-private, no hazard)
        {
            float* Xw = smem + q * 1040 + ((b + 1) & 1) * 520;
            #pragma unroll
            for (int m = 0; m < 4; ++m) {
                Xw[((l & 1) * 4 + m) * 65 + (l >> 1)]      = g0[m];
                Xw[((l & 1) * 4 + m) * 65 + 32 + (l >> 1)] = g1[m];
            }
        }

        STEP_L(B0, c0 + 4)
        STEP_L(B1, c0 + 5)
        STEP_L(B2, c0 + 6)
        STEP_L(B3, c0 + 7)
    }

    // ---- peeled batch b=7: steps 56..63 ----
    STEP_L(B0, 56)
    STEP_L(B1, 57)
    STEP_L(B2, 58)
    STEP_L(B3, 59)
    STEP_N(B0, 60)
    STEP_N(B1, 61)
    STEP_N(B2, 62)
    STEP_N(B3, 63)

    __syncthreads();

    // ---- 3-phase tree reduction over the 8 wave partials (8->4->2->1) ----
    float* R = smem;
    if (q >= 4) dumpAcc(R + (q - 4) * 4096, acc, l);
    __syncthreads();
    if (q < 4) addAcc(R + q * 4096, acc, l);
    __syncthreads();
    if (q == 2 || q == 3) dumpAcc(R + (q - 2) * 4096, acc, l);
    __syncthreads();
    if (q < 2) addAcc(R + q * 4096, acc, l);
    __syncthreads();
    if (q == 1) dumpAcc(R, acc, l);
    __syncthreads();
    if (q == 0) {
        addAcc(R, acc, l);
        #pragma unroll
        for (int mt = 0; mt < 2; ++mt) {
            #pragma unroll
            for (int f = 0; f < 2; ++f) {
                const float bv = bias[f * 32 + lane31];
                #pragma unroll
                for (int r = 0; r < 16; ++r) {
                    const int orow = mt * 32 + (r & 3) + 8 * (r >> 2) + 4 * h;
                    out[(size_t)(row0 + orow) * N_O + f * 32 + lane31] =
                        acc[mt * 2 + f][r] + bv;
                }
            }
        }
    }
}

extern "C" void kernel_launch(void* const* d_in, const int* in_sizes, int n_in,
                              void* d_out, int out_size, void* d_ws, size_t ws_size,
                              hipStream_t stream) {
    const float* X    = (const float*)d_in[0];   // (32768, 512) f32
    const float* C    = (const float*)d_in[1];   // (2, 512, 64, 8) f32
    const float* bias = (const float*)d_in[2];   // (64,) f32
    float* out = (float*)d_out;                  // (32768, 64) f32
    int4* ws = (int4*)d_ws;                      // 1 MB bf16 wave-contiguous weights

    fkan_prep<<<256, 256, 0, stream>>>(C, ws);
    fkan_main<<<512, 512, 0, stream>>>(X, (const i32x4*)ws, bias, out);
}

// Round 7
// 295.843 us; speedup vs baseline: 1.2755x; 1.2755x over previous
//
#include <hip/hip_runtime.h>
#include <hip/hip_bf16.h>

// Fourier-KAN, round 7: GEMM M=32768 N=64 K=8192 with on-the-fly A.
// Math/fragments identical to verified rounds 2-6 (absmax 0.03125):
//   k = i*16 + t*8 + g; mfma_f32_32x32x16_bf16; A/B slot-symmetric k map;
//   C/D col=lane&31, row=(reg&3)+8*(reg>>2)+4*(lane>>5).
// Structure: wave-contiguous K-split (wave q owns i in [64q,64q+64)), zero
// barriers in the main loop.
//  - B: global->reg coalesced 16B/lane from the wave's contiguous 128KB ws
//    stream, DISTANCE-2 named slots (16 VGPRs — round 5 proved no spill;
//    round 6's distance-4 + X regs spilled and died on scratch traffic).
//  - X: coalesced float4 loads -> wave-private LDS transpose (stride 64,
//    2-way-free banks), double-buffered per 8-i batch, wave-synchronous.
//  - LDS: 32KB X + 64KB reduction overlay (reused) = 64KB -> 2 blocks/CU.

#define N_B 32768
#define N_I 512
#define N_O 64

typedef short bf16x8 __attribute__((ext_vector_type(8)));
typedef float f32x4  __attribute__((ext_vector_type(4)));
typedef float f32x16 __attribute__((ext_vector_type(16)));
typedef int   i32x4  __attribute__((ext_vector_type(4)));

// hardware packed f32->bf16 (RNE)
__device__ __forceinline__ int cvtpk(float lo, float hi) {
    int r;
    asm("v_cvt_pk_bf16_f32 %0, %1, %2" : "=v"(r) : "v"(lo), "v"(hi));
    return r;
}

// ---------------- prep: C (f32) -> ws (bf16, wave-contiguous streams) --------
// ws 16B-slot [q*8192 + c*128 + f*64 + l] = bf16( C[t=l>>5][i=q*64+c][n=f*32+(l&31)][g=0..7] )
__global__ __launch_bounds__(256)
void fkan_prep(const float* __restrict__ C, int4* __restrict__ ws) {
    const int tid = blockIdx.x * 256 + threadIdx.x;   // 65536 threads
    const int t = tid >> 15;
    const int i = (tid >> 6) & 511;
    const int n = tid & 63;
    const float* src = C + ((size_t)(t * N_I + i) * N_O + n) * 8;
    const float4 v0 = *(const float4*)(src);
    const float4 v1 = *(const float4*)(src + 4);
    int4 w;
    w.x = cvtpk(v0.x, v0.y);
    w.y = cvtpk(v0.z, v0.w);
    w.z = cvtpk(v1.x, v1.y);
    w.w = cvtpk(v1.z, v1.w);
    const int q = i >> 6, c = i & 63, f = n >> 5, l = t * 32 + (n & 31);
    ws[q * 8192 + c * 128 + f * 64 + l] = w;
}

// ---------------- main ----------------
// branchless cos/sin Chebyshev chain -> packed bf16 A-fragment (freqs 1..8)
__device__ __forceinline__ bf16x8 trigfrag(float x, int h) {
    const float r  = x * 0.15915494309189535f;   // revolutions
    const float s1 = __builtin_amdgcn_sinf(r);
    const float c1 = __builtin_amdgcn_cosf(r);
    const float t2 = c1 + c1;
    const float p0 = h ? 0.f : 1.f;
    const float p1 = h ? s1  : c1;
    const float p2 = __builtin_fmaf(t2, p1, -p0);
    const float p3 = __builtin_fmaf(t2, p2, -p1);
    const float p4 = __builtin_fmaf(t2, p3, -p2);
    const float p5 = __builtin_fmaf(t2, p4, -p3);
    const float p6 = __builtin_fmaf(t2, p5, -p4);
    const float p7 = __builtin_fmaf(t2, p6, -p5);
    const float p8 = __builtin_fmaf(t2, p7, -p6);
    union { int d[4]; bf16x8 v; } u;
    u.d[0] = cvtpk(p1, p2);
    u.d[1] = cvtpk(p3, p4);
    u.d[2] = cvtpk(p5, p6);
    u.d[3] = cvtpk(p7, p8);
    return u.v;
}

// one K-step: 2 B-frags (regs), 2 A-frags (trig), 4 MFMAs
__device__ __forceinline__ void compute4(i32x4 b0r, i32x4 b1r, float xa, float xb,
                                         int h, f32x16* acc) {
    union { i32x4 d; bf16x8 v; } u0, u1;
    u0.d = b0r; u1.d = b1r;
    const bf16x8 A0 = trigfrag(xa, h);
    const bf16x8 A1 = trigfrag(xb, h);
    __builtin_amdgcn_s_setprio(1);
    acc[0] = __builtin_amdgcn_mfma_f32_32x32x16_bf16(A0, u0.v, acc[0], 0, 0, 0);
    acc[1] = __builtin_amdgcn_mfma_f32_32x32x16_bf16(A0, u1.v, acc[1], 0, 0, 0);
    acc[2] = __builtin_amdgcn_mfma_f32_32x32x16_bf16(A1, u0.v, acc[2], 0, 0, 0);
    acc[3] = __builtin_amdgcn_mfma_f32_32x32x16_bf16(A1, u1.v, acc[3], 0, 0, 0);
    __builtin_amdgcn_s_setprio(0);
}

__device__ __forceinline__ void dumpAcc(float* base, const f32x16* acc, int l) {
    #pragma unroll
    for (int fr = 0; fr < 4; ++fr) {
        union { f32x16 v; f32x4 s[4]; } u; u.v = acc[fr];
        #pragma unroll
        for (int rg = 0; rg < 4; ++rg)
            *(f32x4*)(base + fr * 1024 + rg * 256 + l * 4) = u.s[rg];
    }
}
__device__ __forceinline__ void addAcc(const float* base, f32x16* acc, int l) {
    #pragma unroll
    for (int fr = 0; fr < 4; ++fr) {
        union { f32x16 v; f32x4 s[4]; } u; u.v = acc[fr];
        #pragma unroll
        for (int rg = 0; rg < 4; ++rg)
            u.s[rg] += *(const f32x4*)(base + fr * 1024 + rg * 256 + l * 4);
        acc[fr] = u.v;
    }
}

// step j (0..7) within the current batch: use slot S, refill with step j+2
#define STEP_L(S, j)                                                        \
    {                                                                       \
        const float xa_ = Xcur[(j) * 64 + lane31];                          \
        const float xb_ = Xcur[(j) * 64 + 32 + lane31];                     \
        compute4(S##a, S##b, xa_, xb_, h, acc);                             \
        S##a = bb[((j) + 2) * 128];                                         \
        S##b = bb[((j) + 2) * 128 + 64];                                    \
    }
// tail step: no refill
#define STEP_N(S, j)                                                        \
    {                                                                       \
        const float xa_ = Xcur[(j) * 64 + lane31];                          \
        const float xb_ = Xcur[(j) * 64 + 32 + lane31];                     \
        compute4(S##a, S##b, xa_, xb_, h, acc);                             \
    }

__global__ __launch_bounds__(512, 4)
void fkan_main(const float* __restrict__ X, const i32x4* __restrict__ Wf,
               const float* __restrict__ bias, float* __restrict__ out) {
    __shared__ __align__(16) float smem[16384];   // 32KB X staging + 64KB reduction overlay

    const int tid    = threadIdx.x;
    const int l      = tid & 63;
    const int q      = tid >> 6;     // wave id; owns i in [64q, 64q+64)
    const int h      = l >> 5;       // 0: cos, 1: sin
    const int lane31 = l & 31;
    const int row0   = blockIdx.x * 64;

    float* Xbase = smem + q * 1024;                // 2 bufs x 8 ilocs x 64 rows
    const i32x4* bptr = Wf + q * 8192 + l;         // contiguous per-wave B stream

    // coalesced X batch sources: lane pair covers one row's 8 floats
    const float* xg0 = X + (size_t)(row0 + (l >> 1)) * N_I + q * 64 + (l & 1) * 4;
    const float* xg1 = xg0 + (size_t)32 * N_I;

    f32x16 acc[4];
    #pragma unroll
    for (int a = 0; a < 4; ++a)
        #pragma unroll
        for (int r = 0; r < 16; ++r) acc[a][r] = 0.f;

    // ---- prologue: X batch 0 -> buf0 (wave-private, no barrier) ----
    {
        const f32x4 g0 = *(const f32x4*)(xg0);
        const f32x4 g1 = *(const f32x4*)(xg1);
        #pragma unroll
        for (int m = 0; m < 4; ++m) {
            Xbase[((l & 1) * 4 + m) * 64 + (l >> 1)]      = g0[m];
            Xbase[((l & 1) * 4 + m) * 64 + 32 + (l >> 1)] = g1[m];
        }
    }
    // ---- prologue: B chunks 0,1 into the two named slots ----
    i32x4 B0a = bptr[0],   B0b = bptr[64];
    i32x4 B1a = bptr[128], B1b = bptr[128 + 64];

    // ---- barrier-free main loop: batches b=0..6 (8 chunks each) ----
    #pragma unroll 1
    for (int b = 0; b < 7; ++b) {
        const i32x4* bb = bptr + b * 1024;         // chunk (b*8) base
        const float* Xcur = Xbase + (b & 1) * 512;
        // issue next X batch loads early (latency hides under steps 0..3)
        const f32x4 g0 = *(const f32x4*)(xg0 + (b + 1) * 8);
        const f32x4 g1 = *(const f32x4*)(xg1 + (b + 1) * 8);

        STEP_L(B0, 0)
        STEP_L(B1, 1)
        STEP_L(B0, 2)
        STEP_L(B1, 3)

        // write next X batch into the other buffer (wave-private, in-order)
        {
            float* Xw = Xbase + ((b + 1) & 1) * 512;
            #pragma unroll
            for (int m = 0; m < 4; ++m) {
                Xw[((l & 1) * 4 + m) * 64 + (l >> 1)]      = g0[m];
                Xw[((l & 1) * 4 + m) * 64 + 32 + (l >> 1)] = g1[m];
            }
        }

        STEP_L(B0, 4)
        STEP_L(B1, 5)
        STEP_L(B0, 6)
        STEP_L(B1, 7)
    }

    // ---- peeled batch b=7: chunks 56..63, refills stop at chunk 63 ----
    {
        const i32x4* bb = bptr + 7 * 1024;
        const float* Xcur = Xbase + 512;
        STEP_L(B0, 0)
        STEP_L(B1, 1)
        STEP_L(B0, 2)
        STEP_L(B1, 3)
        STEP_L(B0, 4)
        STEP_L(B1, 5)   // refills chunk 63 into B1
        STEP_N(B0, 6)
        STEP_N(B1, 7)
    }

    __syncthreads();

    // ---- 3-phase tree reduction over the 8 wave partials (8->4->2->1) ----
    float* R = smem;
    if (q >= 4) dumpAcc(R + (q - 4) * 4096, acc, l);
    __syncthreads();
    if (q < 4) addAcc(R + q * 4096, acc, l);
    __syncthreads();
    if (q == 2 || q == 3) dumpAcc(R + (q - 2) * 4096, acc, l);
    __syncthreads();
    if (q < 2) addAcc(R + q * 4096, acc, l);
    __syncthreads();
    if (q == 1) dumpAcc(R, acc, l);
    __syncthreads();
    if (q == 0) {
        addAcc(R, acc, l);
        #pragma unroll
        for (int mt = 0; mt < 2; ++mt) {
            #pragma unroll
            for (int f = 0; f < 2; ++f) {
                const float bv = bias[f * 32 + lane31];
                #pragma unroll
                for (int r = 0; r < 16; ++r) {
                    const int orow = mt * 32 + (r & 3) + 8 * (r >> 2) + 4 * h;
                    out[(size_t)(row0 + orow) * N_O + f * 32 + lane31] =
                        acc[mt * 2 + f][r] + bv;
                }
            }
        }
    }
}

extern "C" void kernel_launch(void* const* d_in, const int* in_sizes, int n_in,
                              void* d_out, int out_size, void* d_ws, size_t ws_size,
                              hipStream_t stream) {
    const float* X    = (const float*)d_in[0];   // (32768, 512) f32
    const float* C    = (const float*)d_in[1];   // (2, 512, 64, 8) f32
    const float* bias = (const float*)d_in[2];   // (64,) f32
    float* out = (float*)d_out;                  // (32768, 64) f32
    int4* ws = (int4*)d_ws;                      // 1 MB bf16 wave-contiguous weights

    fkan_prep<<<256, 256, 0, stream>>>(C, ws);
    fkan_main<<<512, 512, 0, stream>>>(X, (const i32x4*)ws, bias, out);
}